// Round 5
// baseline (334.917 us; speedup 1.0000x reference)
//
#include <hip/hip_runtime.h>
#include <stdint.h>

#define H_DIM 1024
#define I_DIM 4096
#define E_NUM 8
#define CAP   1024

typedef __attribute__((ext_vector_type(8))) short bf16x8;
typedef __attribute__((ext_vector_type(4))) float f32x4;

#define AS1 __attribute__((address_space(1)))
#define AS3 __attribute__((address_space(3)))

__device__ __forceinline__ unsigned short f2bf(float f){
  union { float f; uint32_t u; } v; v.f = f;
  uint32_t u = v.u;
  uint32_t r = (u + 0x7FFFu + ((u >> 16) & 1u)) >> 16;
  return (unsigned short)r;
}

// ---------------- zero output ----------------
__global__ void zero_kernel(float4* __restrict__ p, int n4){
  int i = blockIdx.x*blockDim.x + threadIdx.x;
  int stride = gridDim.x*blockDim.x;
  float4 z; z.x=0.f; z.y=0.f; z.z=0.f; z.w=0.f;
  for (; i < n4; i += stride) p[i] = z;
}

// ---------------- router softmax + x -> bf16 (first CAP tokens) ----------------
__global__ __launch_bounds__(256) void router_kernel(
    const float* __restrict__ x, const float* __restrict__ rw_w,
    const float* __restrict__ rb, unsigned short* __restrict__ xb,
    float* __restrict__ rwout)
{
  int c = blockIdx.x;
  int t = threadIdx.x;
  float acc[E_NUM];
  #pragma unroll
  for (int e=0;e<E_NUM;e++) acc[e]=0.f;
  const float* xr = x + (size_t)c*H_DIM;
  for (int h=t; h<H_DIM; h+=256){
    float xv = xr[h];
    xb[(size_t)c*H_DIM + h] = f2bf(xv);
    #pragma unroll
    for (int e=0;e<E_NUM;e++) acc[e] += xv * rw_w[e*H_DIM + h];
  }
  __shared__ float part[256][E_NUM];
  #pragma unroll
  for (int e=0;e<E_NUM;e++) part[t][e]=acc[e];
  __syncthreads();
  for (int s=128; s>0; s>>=1){
    if (t<s){
      #pragma unroll
      for (int e=0;e<E_NUM;e++) part[t][e]+=part[t+s][e];
    }
    __syncthreads();
  }
  if (t==0){
    float l[E_NUM], mx=-1e30f;
    #pragma unroll
    for (int e=0;e<E_NUM;e++){ l[e]=part[0][e]+rb[e]; mx=fmaxf(mx,l[e]); }
    float s=0.f;
    #pragma unroll
    for (int e=0;e<E_NUM;e++){ l[e]=expf(l[e]-mx); s+=l[e]; }
    float inv = 1.f/s;
    #pragma unroll
    for (int e=0;e<E_NUM;e++) rwout[c*E_NUM+e] = l[e]*inv;
  }
}

// ---------------- fp32 -> bf16 transpose (src RxC -> dst CxR) ----------------
__global__ __launch_bounds__(256) void transpose_cvt(
    const float* __restrict__ src, unsigned short* __restrict__ dst,
    int R, int C, long srcZ, long dstZ)
{
  src += (size_t)blockIdx.z * srcZ;
  dst += (size_t)blockIdx.z * dstZ;
  __shared__ float tile[32][33];
  int c0 = blockIdx.x*32, r0 = blockIdx.y*32;
  int tx = threadIdx.x, ty = threadIdx.y;
  #pragma unroll
  for (int j=ty; j<32; j+=8)
    tile[j][tx] = src[(size_t)(r0+j)*C + c0+tx];
  __syncthreads();
  #pragma unroll
  for (int j=ty; j<32; j+=8)
    dst[(size_t)(c0+j)*R + r0+tx] = f2bf(tile[tx][j]);
}

// ---- 128x128 bf16 GEMM (m97 structure), B N-major, BK=64, single-buffer ----
// 4 waves (2x2), 32KB LDS, 2 syncthreads per K-step, ~3 blocks/CU for TLP.
// T1 XCD swizzle (m fastest within XCD chunk), T2 XOR swizzle (R2-proven,
// 0 conflicts): read slot (kk*4+lq)^(lrow&7), staging source pre-swizzled
// with the same involution, LDS dest linear.
// MODE 0: relu*rw -> bf16 inter.  MODE 1: atomicAdd fp32.
template<int MODE>
__global__ __launch_bounds__(256) void gemm_bt2(
    const unsigned short* __restrict__ A, int lda, long aZ,
    const unsigned short* __restrict__ B, int ldb, long bZ,
    int NS, int tilesPerZ,
    const float* __restrict__ rw,
    unsigned short* __restrict__ outInter,
    float* __restrict__ outAdd)
{
  __shared__ unsigned short As[128*64];
  __shared__ unsigned short Bs[128*64];

  // T1: XCD-aware swizzle (nwg % 8 == 0), m-tiles fastest inside a chunk
  int nwg = gridDim.x;
  int id  = blockIdx.x;
  int swz = (id & 7)*(nwg >> 3) + (id >> 3);
  int z   = swz / tilesPerZ;
  int rr_ = swz - z*tilesPerZ;
  int mt  = rr_ & 7, nt = rr_ >> 3;
  int m0  = mt*128, n0 = nt*128;

  const unsigned short* Ab = A + (size_t)z*aZ + (size_t)m0*lda;
  const unsigned short* Bb = B + (size_t)z*bZ + (size_t)n0*ldb;

  int tid  = threadIdx.x;
  int w    = tid >> 6, l = tid & 63;
  int wr   = w >> 1,  wc = w & 1;       // wave grid 2x2, each 64x64 out
  int lrow = l & 15,  lq = l >> 4;
  int r7   = lrow & 7;

  // staging: wave w covers rows [w*32, w*32+32); instr i rows w*32+i*8+(l>>3)
  int srow  = (l >> 3);
  int sslot = ((l & 7) ^ ((l >> 3) & 7)) * 8;   // inverse-swizzled source elems
  int ldsRow0 = w*32;                            // +i*8

  f32x4 acc[4][4];
  #pragma unroll
  for (int i=0;i<4;i++)
    #pragma unroll
    for (int j=0;j<4;j++)
      acc[i][j] = (f32x4){0.f,0.f,0.f,0.f};

  for (int s=0; s<NS; ++s){
    int kt = s*64;
    #pragma unroll
    for (int i=0;i<4;i++){
      int r = ldsRow0 + i*8 + srow;
      __builtin_amdgcn_global_load_lds(
        (const AS1 void*)(Ab + (size_t)r*lda + kt + sslot),
        (AS3 void*)(&As[r*64 + (l&7)*8]), 16, 0, 0);
      __builtin_amdgcn_global_load_lds(
        (const AS1 void*)(Bb + (size_t)r*ldb + kt + sslot),
        (AS3 void*)(&Bs[r*64 + (l&7)*8]), 16, 0, 0);
    }
    __syncthreads();   // drain: tiles ready for all waves

    bf16x8 af[4][2], bf[4][2];
    #pragma unroll
    for (int f=0;f<4;f++){
      int ra = (wr*64 + f*16 + lrow)*128;   // byte row base (64 elems * 2B)
      int rb = (wc*64 + f*16 + lrow)*128;
      #pragma unroll
      for (int kk=0;kk<2;kk++){
        int slot = ((kk*4+lq) ^ r7) << 4;
        af[f][kk] = *(const bf16x8*)((const char*)As + ra + slot);
        bf[f][kk] = *(const bf16x8*)((const char*)Bs + rb + slot);
      }
    }

    #pragma unroll
    for (int kk=0;kk<2;kk++)
      #pragma unroll
      for (int fm=0;fm<4;fm++)
        #pragma unroll
        for (int fn=0;fn<4;fn++)
          acc[fm][fn] = __builtin_amdgcn_mfma_f32_16x16x32_bf16(af[fm][kk], bf[fn][kk], acc[fm][fn], 0, 0, 0);

    __syncthreads();   // protect LDS before next stage
  }

  // epilogue: C/D layout col = lane&15, row = (lane>>4)*4 + reg
  #pragma unroll
  for (int fm=0;fm<4;fm++){
    #pragma unroll
    for (int fn=0;fn<4;fn++){
      #pragma unroll
      for (int rg=0;rg<4;rg++){
        int gm = m0 + wr*64 + fm*16 + lq*4 + rg;
        int gn = n0 + wc*64 + fn*16 + lrow;
        float v = acc[fm][fn][rg];
        if (MODE==0){
          v = fmaxf(v, 0.f) * rw[gm*E_NUM + z];
          outInter[(size_t)gm*(E_NUM*I_DIM) + (size_t)z*I_DIM + gn] = f2bf(v);
        } else {
          atomicAdd(&outAdd[(size_t)gm*H_DIM + gn], v);
        }
      }
    }
  }
}

extern "C" void kernel_launch(void* const* d_in, const int* in_sizes, int n_in,
                              void* d_out, int out_size, void* d_ws, size_t ws_size,
                              hipStream_t stream)
{
  const float* x   = (const float*)d_in[0];
  const float* rww = (const float*)d_in[1];
  const float* rwb = (const float*)d_in[2];
  const float* w1  = (const float*)d_in[3];  // (E, H, I)
  const float* w2  = (const float*)d_in[4];  // (E, I, H)
  float* out = (float*)d_out;

  char* ws = (char*)d_ws;
  float*          rwout = (float*)(ws);                         // 32 KB
  unsigned short* xb    = (unsigned short*)(ws + (1u<<16));     // 2 MB  @64KB
  unsigned short* inter = (unsigned short*)(ws + (4ull<<20));   // 64 MB @4MB
  unsigned short* wt    = (unsigned short*)(ws + (68ull<<20));  // 64 MB @68MB
  const size_t needed = 132ull<<20;

  zero_kernel<<<2048, 256, 0, stream>>>((float4*)out, out_size/4);
  if (ws_size < needed) return;

  router_kernel<<<CAP, 256, 0, stream>>>(x, rww, rwb, xb, rwout);

  dim3 tb(32,8);
  // W1 (E,H,I) -> W1^T per expert (I x H) bf16
  transpose_cvt<<<dim3(I_DIM/32, H_DIM/32, E_NUM), tb, 0, stream>>>(
      w1, wt, H_DIM, I_DIM, (long)H_DIM*I_DIM, (long)I_DIM*H_DIM);

  // GEMM1: inter[c, e*I+n] = bf16( relu( xb @ W1_e^T ) * rw[c,e] )
  // grid 2048 = (8 mtiles x 32 ntiles) x 8 experts; K=1024 -> NS=16
  gemm_bt2<0><<<2048, 256, 0, stream>>>(
      xb, H_DIM, 0L,
      wt, H_DIM, (long)I_DIM*H_DIM,
      16, 256, rwout, inter, nullptr);

  // W2 flat (E*I x H) -> W2^T (H x E*I) bf16
  transpose_cvt<<<dim3(H_DIM/32, (E_NUM*I_DIM)/32, 1), tb, 0, stream>>>(
      w2, wt, E_NUM*I_DIM, H_DIM, 0L, 0L);

  // GEMM2: out[c,h] += inter[c,:] @ W2^T[h,:]; split-K z=16 slices of 2048 -> NS=32
  // grid 1024 = (8 mtiles x 8 ntiles) x 16 z
  gemm_bt2<1><<<1024, 256, 0, stream>>>(
      inter, E_NUM*I_DIM, 2048L,
      wt,    E_NUM*I_DIM, 2048L,
      32, 64, nullptr, nullptr, out);
}

// Round 6
// 274.607 us; speedup vs baseline: 1.2196x; 1.2196x over previous
//
#include <hip/hip_runtime.h>
#include <stdint.h>

#define H_DIM 1024
#define I_DIM 4096
#define E_NUM 8
#define CAP   1024

typedef __attribute__((ext_vector_type(8))) short bf16x8;
typedef __attribute__((ext_vector_type(16))) float f32x16;

#define AS1 __attribute__((address_space(1)))
#define AS3 __attribute__((address_space(3)))

__device__ __forceinline__ unsigned short f2bf(float f){
  union { float f; uint32_t u; } v; v.f = f;
  uint32_t u = v.u;
  uint32_t r = (u + 0x7FFFu + ((u >> 16) & 1u)) >> 16;
  return (unsigned short)r;
}

// ---------------- zero output ----------------
__global__ void zero_kernel(float4* __restrict__ p, int n4){
  int i = blockIdx.x*blockDim.x + threadIdx.x;
  int stride = gridDim.x*blockDim.x;
  float4 z; z.x=0.f; z.y=0.f; z.z=0.f; z.w=0.f;
  for (; i < n4; i += stride) p[i] = z;
}

// ---------------- router softmax + x -> bf16 (first CAP tokens) ----------------
__global__ __launch_bounds__(256) void router_kernel(
    const float* __restrict__ x, const float* __restrict__ rw_w,
    const float* __restrict__ rb, unsigned short* __restrict__ xb,
    float* __restrict__ rwout)
{
  int c = blockIdx.x;
  int t = threadIdx.x;
  float acc[E_NUM];
  #pragma unroll
  for (int e=0;e<E_NUM;e++) acc[e]=0.f;
  const float* xr = x + (size_t)c*H_DIM;
  for (int h=t; h<H_DIM; h+=256){
    float xv = xr[h];
    xb[(size_t)c*H_DIM + h] = f2bf(xv);
    #pragma unroll
    for (int e=0;e<E_NUM;e++) acc[e] += xv * rw_w[e*H_DIM + h];
  }
  __shared__ float part[256][E_NUM];
  #pragma unroll
  for (int e=0;e<E_NUM;e++) part[t][e]=acc[e];
  __syncthreads();
  for (int s=128; s>0; s>>=1){
    if (t<s){
      #pragma unroll
      for (int e=0;e<E_NUM;e++) part[t][e]+=part[t+s][e];
    }
    __syncthreads();
  }
  if (t==0){
    float l[E_NUM], mx=-1e30f;
    #pragma unroll
    for (int e=0;e<E_NUM;e++){ l[e]=part[0][e]+rb[e]; mx=fmaxf(mx,l[e]); }
    float s=0.f;
    #pragma unroll
    for (int e=0;e<E_NUM;e++){ l[e]=expf(l[e]-mx); s+=l[e]; }
    float inv = 1.f/s;
    #pragma unroll
    for (int e=0;e<E_NUM;e++) rwout[c*E_NUM+e] = l[e]*inv;
  }
}

// ------- fp32 -> bf16 transpose, 64x64 tile, float4 loads / ushort4 stores -------
__global__ __launch_bounds__(256) void transpose_cvt64(
    const float* __restrict__ src, unsigned short* __restrict__ dst,
    int R, int C, long srcZ, long dstZ)
{
  src += (size_t)blockIdx.z * srcZ;
  dst += (size_t)blockIdx.z * dstZ;
  __shared__ float tile[64][65];
  int c0 = blockIdx.x*64, r0 = blockIdx.y*64;
  int t  = threadIdx.x;
  int tx = t & 15, ty = t >> 4;
  #pragma unroll
  for (int p=0;p<4;p++){
    int r = ty + p*16;
    float4 v = *(const float4*)(src + (size_t)(r0+r)*C + c0 + tx*4);
    tile[r][tx*4+0]=v.x; tile[r][tx*4+1]=v.y; tile[r][tx*4+2]=v.z; tile[r][tx*4+3]=v.w;
  }
  __syncthreads();
  #pragma unroll
  for (int p=0;p<4;p++){
    int c = ty + p*16;
    ushort4 o;
    o.x = f2bf(tile[tx*4+0][c]);
    o.y = f2bf(tile[tx*4+1][c]);
    o.z = f2bf(tile[tx*4+2][c]);
    o.w = f2bf(tile[tx*4+3][c]);
    *(ushort4*)(dst + (size_t)(c0+c)*R + r0 + tx*4) = o;
  }
}

// ---- 256x256 bf16 GEMM, B N-major; R3 counted pipeline + 32x32x16 MFMA ----
// 4 LDS buffers x 32KB (A[256x32]+B[256x32]), depth-3 prefetch, vmcnt(8) at
// each half boundary (never 0 in steady state), 1 barrier per half, 16 MFMA
// (32x32x16) per half per wave under setprio.
// MODE 0: relu*rw -> bf16 inter.  MODE 1: atomicAdd fp32.
template<int MODE>
__global__ __launch_bounds__(512, 2) void gemm4b(
    const unsigned short* __restrict__ A, int lda, long aZ,
    const unsigned short* __restrict__ B, int ldb, long bZ,
    int NH, int tilesPerZ,
    const float* __restrict__ rw,
    unsigned short* __restrict__ outInter,
    float* __restrict__ outAdd)
{
  extern __shared__ char smem[];   // 131072 = 4 bufs x (A 16KB | B 16KB)

  // T1: XCD-aware swizzle (gridDim.x % 8 == 0)
  int nwg = gridDim.x;
  int id  = blockIdx.x;
  int swz = (id & 7)*(nwg >> 3) + (id >> 3);
  int z   = swz / tilesPerZ;
  int rr_ = swz - z*tilesPerZ;
  int mt  = rr_ & 3, nt = rr_ >> 2;
  int m0  = mt*256, n0 = nt*256;

  const unsigned short* Ab = A + (size_t)z*aZ + (size_t)m0*lda;
  const unsigned short* Bb = B + (size_t)z*bZ + (size_t)n0*ldb;

  int tid  = threadIdx.x;
  int w    = tid >> 6, l = tid & 63;
  int wr   = w >> 2,  wc = w & 3;       // wave grid 2M x 4N, wave out 128x64

  // staging: wave w covers rows [w*32, w*32+32) of both A and B halves.
  // LDS[row][slot] holds global slot (slot ^ ((row>>1)&3)); dest linear.
  int srow  = (l >> 2);
  int sslot = ((l & 3) ^ ((l >> 3) & 3)) * 8;   // inverse-swizzled source slot
  size_t aOff0 = (size_t)(w*32 + srow)      * lda + sslot;
  size_t aOff1 = (size_t)(w*32 + 16 + srow) * lda + sslot;
  size_t bOff0 = (size_t)(w*32 + srow)      * ldb + sslot;
  size_t bOff1 = (size_t)(w*32 + 16 + srow) * ldb + sslot;
  int ldsA0 = (w*32)*64, ldsA1 = (w*32+16)*64;

  auto stageHalf = [&](int h){
    char* lb = smem + ((h & 3) << 15);
    int kb = h << 5;
    __builtin_amdgcn_global_load_lds((const AS1 void*)(Ab + aOff0 + kb),
        (AS3 void*)(lb + ldsA0), 16, 0, 0);
    __builtin_amdgcn_global_load_lds((const AS1 void*)(Ab + aOff1 + kb),
        (AS3 void*)(lb + ldsA1), 16, 0, 0);
    __builtin_amdgcn_global_load_lds((const AS1 void*)(Bb + bOff0 + kb),
        (AS3 void*)(lb + 16384 + ldsA0), 16, 0, 0);
    __builtin_amdgcn_global_load_lds((const AS1 void*)(Bb + bOff1 + kb),
        (AS3 void*)(lb + 16384 + ldsA1), 16, 0, 0);
  };

  f32x16 acc[4][2];
  #pragma unroll
  for (int i=0;i<4;i++)
    #pragma unroll
    for (int j=0;j<2;j++)
      acc[i][j] = (f32x16){0.f,0.f,0.f,0.f,0.f,0.f,0.f,0.f,
                           0.f,0.f,0.f,0.f,0.f,0.f,0.f,0.f};

  // 32x32x16 fragment addressing: row = base + (l&31), k-slot = l>>5,
  // read slot = (kk*2 + (l>>5)) ^ ((l>>1)&3)  [matches staging involution]
  int arow = wr*128 + (l&31);
  int brow = wc*64  + (l&31);
  int ksl  = l >> 5;
  int sw   = (l >> 1) & 3;

  auto compute = [&](int h){
    char* lb = smem + ((h & 3) << 15);
    bf16x8 af[4][2], bfq[2][2];
    #pragma unroll
    for (int fa=0; fa<4; fa++)
      #pragma unroll
      for (int kk=0; kk<2; kk++)
        af[fa][kk] = *(const bf16x8*)(lb + (arow + fa*32)*64 + (((kk*2 + ksl) ^ sw) << 4));
    #pragma unroll
    for (int fb=0; fb<2; fb++)
      #pragma unroll
      for (int kk=0; kk<2; kk++)
        bfq[fb][kk] = *(const bf16x8*)(lb + 16384 + (brow + fb*32)*64 + (((kk*2 + ksl) ^ sw) << 4));
    __builtin_amdgcn_s_setprio(1);
    #pragma unroll
    for (int kk=0;kk<2;kk++)
      #pragma unroll
      for (int fa=0;fa<4;fa++)
        #pragma unroll
        for (int fb=0;fb<2;fb++)
          acc[fa][fb] = __builtin_amdgcn_mfma_f32_32x32x16_bf16(af[fa][kk], bfq[fb][kk], acc[fa][fb], 0, 0, 0);
    __builtin_amdgcn_s_setprio(0);
  };

  // prologue: depth-3 prefetch
  stageHalf(0); stageHalf(1); stageHalf(2);

  int h = 0;
  for (; h < NH-2; ++h){
    asm volatile("s_waitcnt vmcnt(8)" ::: "memory");
    __builtin_amdgcn_s_barrier();
    if (h+3 < NH) stageHalf(h+3);
    compute(h);
  }
  asm volatile("s_waitcnt vmcnt(4)" ::: "memory");
  __builtin_amdgcn_s_barrier();
  compute(NH-2);
  asm volatile("s_waitcnt vmcnt(0)" ::: "memory");
  __builtin_amdgcn_s_barrier();
  compute(NH-1);

  // epilogue: 32x32 C/D layout col = l&31, row = (reg&3) + 8*(reg>>2) + 4*(l>>5)
  #pragma unroll
  for (int fa=0; fa<4; fa++){
    #pragma unroll
    for (int fb=0; fb<2; fb++){
      #pragma unroll
      for (int rg=0; rg<16; rg++){
        int gm = m0 + wr*128 + fa*32 + (rg&3) + 8*(rg>>2) + 4*(l>>5);
        int gn = n0 + wc*64  + fb*32 + (l&31);
        float v = acc[fa][fb][rg];
        if (MODE==0){
          v = fmaxf(v, 0.f) * rw[gm*E_NUM + z];
          outInter[(size_t)gm*(E_NUM*I_DIM) + (size_t)z*I_DIM + gn] = f2bf(v);
        } else {
          atomicAdd(&outAdd[(size_t)gm*H_DIM + gn], v);
        }
      }
    }
  }
}

extern "C" void kernel_launch(void* const* d_in, const int* in_sizes, int n_in,
                              void* d_out, int out_size, void* d_ws, size_t ws_size,
                              hipStream_t stream)
{
  const float* x   = (const float*)d_in[0];
  const float* rww = (const float*)d_in[1];
  const float* rwb = (const float*)d_in[2];
  const float* w1  = (const float*)d_in[3];  // (E, H, I)
  const float* w2  = (const float*)d_in[4];  // (E, I, H)
  float* out = (float*)d_out;

  char* ws = (char*)d_ws;
  float*          rwout = (float*)(ws);                         // 32 KB
  unsigned short* xb    = (unsigned short*)(ws + (1u<<16));     // 2 MB  @64KB
  unsigned short* inter = (unsigned short*)(ws + (4ull<<20));   // 64 MB @4MB
  unsigned short* wt    = (unsigned short*)(ws + (68ull<<20));  // 64 MB @68MB
  const size_t needed = 132ull<<20;

  zero_kernel<<<2048, 256, 0, stream>>>((float4*)out, out_size/4);
  if (ws_size < needed) return;

  void* k0 = (void*)gemm4b<0>;
  void* k1 = (void*)gemm4b<1>;
  hipFuncSetAttribute(k0, hipFuncAttributeMaxDynamicSharedMemorySize, 131072);
  hipFuncSetAttribute(k1, hipFuncAttributeMaxDynamicSharedMemorySize, 131072);

  router_kernel<<<CAP, 256, 0, stream>>>(x, rww, rwb, xb, rwout);

  // W1 (E,H,I) -> W1^T per expert (I x H) bf16
  transpose_cvt64<<<dim3(I_DIM/64, H_DIM/64, E_NUM), 256, 0, stream>>>(
      w1, wt, H_DIM, I_DIM, (long)H_DIM*I_DIM, (long)I_DIM*H_DIM);

  // GEMM1: inter[c, e*I+n] = bf16( relu( xb @ W1_e^T ) * rw[c,e] )
  // grid 512 = (4 mtiles x 16 ntiles) x 8 experts; K=1024 -> NH=32
  gemm4b<0><<<512, 512, 131072, stream>>>(
      xb, H_DIM, 0L,
      wt, H_DIM, (long)I_DIM*H_DIM,
      32, 64, rwout, inter, nullptr);

  // W2 flat (E*I x H) -> W2^T (H x E*I) bf16
  transpose_cvt64<<<dim3(H_DIM/64, (E_NUM*I_DIM)/64, 1), 256, 0, stream>>>(
      w2, wt, E_NUM*I_DIM, H_DIM, 0L, 0L);

  // GEMM2: out[c,h] += inter[c,:] @ W2^T[h,:]; split-K z=16 slices of 2048 -> NH=64
  // grid 256 = (4 mtiles x 4 ntiles) x 16 z
  gemm4b<1><<<256, 512, 131072, stream>>>(
      inter, E_NUM*I_DIM, 2048L,
      wt,    E_NUM*I_DIM, 2048L,
      64, 16, nullptr, nullptr, out);
}